// Round 1
// baseline (88.080 us; speedup 1.0000x reference)
//
#include <hip/hip_runtime.h>

// Problem constants (fixed by setup_inputs): n_ptiles=1024, max_src=4,
// n_bands=5, tile_slen=4, ptile_slen=52.
constexpr int NP = 1024;
constexpr int MS = 4;
constexpr int NB = 5;
constexpr int SL = 52;
constexpr int SS = SL * SL; // 2704

// Derivation of the affine sample coords (matches reference exactly in exact
// arithmetic; fp32 rounding differences are far below the 0.157 threshold):
//   l  = (locs*(4/52) + 24/52 - 0.5)*2
//   grid_x[y][x] = mgrid_x[x] - l1,  mgrid_x[x] = ((x-25.5)/25.5)*(51/52) = (x-25.5)/26
//   ix = (grid_x + 1)*0.5*51 = x*(25.5/26) + [(1-l1)*25.5 - 25.5*25.5/26]
// and symmetrically for iy with l0.

__global__ __launch_bounds__(256) void tile_render_kernel(
    const float* __restrict__ locs,
    const float* __restrict__ sources,
    float* __restrict__ out)
{
    __shared__ float smem[MS * SS]; // 43264 B -> 3 blocks/CU

    const int blk = blockIdx.x;
    const int p = blk / NB;
    const int b = blk - p * NB;
    const int tid = threadIdx.x;

    // Stage the 4 source slices sources[p][s][b][:][:] into LDS.
    // Each slice is 2704 contiguous floats, 16B-aligned (2704*4B = 10816 % 16 == 0).
    #pragma unroll
    for (int s = 0; s < MS; ++s) {
        const float4* src = reinterpret_cast<const float4*>(
            sources + ((size_t)(p * MS + s) * NB + b) * SS);
        float4* dst = reinterpret_cast<float4*>(smem + s * SS);
        for (int i = tid; i < SS / 4; i += 256) dst[i] = src[i];
    }

    // Per-source affine params (same 8 locs floats for every thread in the
    // block -> broadcast loads through L1).
    const float A = 25.5f / 26.0f;
    float bx[MS], by[MS];
    #pragma unroll
    for (int s = 0; s < MS; ++s) {
        float loc0 = locs[((size_t)p * MS + s) * 2 + 0];
        float loc1 = locs[((size_t)p * MS + s) * 2 + 1];
        float l0 = (loc0 * (4.0f / 52.0f) + (24.0f / 52.0f) - 0.5f) * 2.0f;
        float l1 = (loc1 * (4.0f / 52.0f) + (24.0f / 52.0f) - 0.5f) * 2.0f;
        bx[s] = (1.0f - l1) * 25.5f - 25.5f * 25.5f / 26.0f; // grid[...,0] uses swapped l
        by[s] = (1.0f - l0) * 25.5f - 25.5f * 25.5f / 26.0f;
    }

    __syncthreads();

    float* outp = out + ((size_t)p * NB + b) * SS;
    for (int pix = tid; pix < SS; pix += 256) {
        int y = pix / SL;
        int x = pix - y * SL;
        float xf = (float)x, yf = (float)y;
        float acc = 0.0f;
        #pragma unroll
        for (int s = 0; s < MS; ++s) {
            float ix = fmaf(xf, A, bx[s]);
            float iy = fmaf(yf, A, by[s]);
            float ix0f = floorf(ix);
            float iy0f = floorf(iy);
            float wx1 = ix - ix0f;
            float wy1 = iy - iy0f;
            float wx0 = 1.0f - wx1;
            float wy0 = 1.0f - wy1;
            int ix0 = (int)ix0f;
            int iy0 = (int)iy0f;
            int ix1 = ix0 + 1;
            int iy1 = iy0 + 1;
            // zeros padding: fold per-corner validity into the 1-D weights
            float mx0 = ((unsigned)ix0 < (unsigned)SL) ? 1.0f : 0.0f;
            float mx1 = ((unsigned)ix1 < (unsigned)SL) ? 1.0f : 0.0f;
            float my0 = ((unsigned)iy0 < (unsigned)SL) ? 1.0f : 0.0f;
            float my1 = ((unsigned)iy1 < (unsigned)SL) ? 1.0f : 0.0f;
            // clamped indices (reference clips then masks — identical result)
            int ix0c = min(max(ix0, 0), SL - 1);
            int ix1c = min(max(ix1, 0), SL - 1);
            int iy0c = min(max(iy0, 0), SL - 1);
            int iy1c = min(max(iy1, 0), SL - 1);
            const float* base = smem + s * SS;
            float v00 = base[iy0c * SL + ix0c];
            float v01 = base[iy0c * SL + ix1c];
            float v10 = base[iy1c * SL + ix0c];
            float v11 = base[iy1c * SL + ix1c];
            float wxa = wx0 * mx0, wxb = wx1 * mx1;
            float wya = wy0 * my0, wyb = wy1 * my1;
            acc = fmaf(v00, wxa * wya, acc);
            acc = fmaf(v01, wxb * wya, acc);
            acc = fmaf(v10, wxa * wyb, acc);
            acc = fmaf(v11, wxb * wyb, acc);
        }
        outp[pix] = acc;
    }
}

extern "C" void kernel_launch(void* const* d_in, const int* in_sizes, int n_in,
                              void* d_out, int out_size, void* d_ws, size_t ws_size,
                              hipStream_t stream) {
    const float* locs = (const float*)d_in[0];
    const float* sources = (const float*)d_in[1];
    float* out = (float*)d_out;
    dim3 grid(NP * NB);
    dim3 block(256);
    hipLaunchKernelGGL(tile_render_kernel, grid, block, 0, stream,
                       locs, sources, out);
}

// Round 2
// 69.529 us; speedup vs baseline: 1.2668x; 1.2668x over previous
//
#include <hip/hip_runtime.h>

// TileRenderer: out[p,b,y,x] = sum_s bilinear_sample(sources[p,s,b], affine(locs[p,s]))
// n_ptiles=1024, max_src=4, n_bands=5, ptile_slen=52.
//
// Affine derivation (exact in real arithmetic):
//   l  = (loc*(4/52) + 24/52 - 0.5)*2
//   ix = x*(25.5/26) + (1-l1)*25.5 - 25.5^2/26   (grid[...,0] uses swapped l)
//   iy = y*(25.5/26) + (1-l0)*25.5 - 25.5^2/26
constexpr int NP = 1024;
constexpr int MS = 4;
constexpr int NB = 5;
constexpr int SL = 52;
constexpr int SS = SL * SL;   // 2704
constexpr int NF4 = SS / 4;   // 676 float4 chunks per slice
constexpr int NTHR = 256;

__device__ __forceinline__ void gload_lds16(const float* g, float* l) {
    __builtin_amdgcn_global_load_lds(
        (const __attribute__((address_space(1))) void*)g,
        (__attribute__((address_space(3))) void*)l,
        16, 0, 0);
}

__global__ __launch_bounds__(NTHR) void tile_render_kernel(
    const float* __restrict__ locs,
    const float* __restrict__ sources,
    float* __restrict__ out)
{
    // Single-source slice: 10816 B -> occupancy is VGPR-bound, not LDS-bound.
    __shared__ __align__(16) float smem[SS];

    const int blk = blockIdx.x;
    const int p = blk / NB;
    const int b = blk - p * NB;
    const int tid = threadIdx.x;

    const float A = 25.5f / 26.0f;
    float bx[MS], by[MS];
    #pragma unroll
    for (int s = 0; s < MS; ++s) {
        float loc0 = locs[(p * MS + s) * 2 + 0];
        float loc1 = locs[(p * MS + s) * 2 + 1];
        float l0 = (loc0 * (4.0f / 52.0f) + (24.0f / 52.0f) - 0.5f) * 2.0f;
        float l1 = (loc1 * (4.0f / 52.0f) + (24.0f / 52.0f) - 0.5f) * 2.0f;
        bx[s] = (1.0f - l1) * 25.5f - 25.5f * 25.5f / 26.0f;
        by[s] = (1.0f - l0) * 25.5f - 25.5f * 25.5f / 26.0f;
    }

    // Each thread owns up to 3 float4 output chunks (676 = 2*256 + 164).
    // Chunk c -> row y = c/13, col start x = (c%13)*4 (52 = 13 chunks/row).
    int ys[3], xs[3];
    bool hasc[3];
    #pragma unroll
    for (int j = 0; j < 3; ++j) {
        int c = tid + j * NTHR;
        hasc[j] = (c < NF4);
        int cc = hasc[j] ? c : 0;
        int y = cc / 13;
        ys[j] = y;
        xs[j] = (cc - y * 13) * 4;
    }

    float acc[3][4];
    #pragma unroll
    for (int j = 0; j < 3; ++j)
        #pragma unroll
        for (int k = 0; k < 4; ++k) acc[j][k] = 0.0f;

    const float* srcbase = sources + (size_t)p * MS * NB * SS + (size_t)b * SS;

    #pragma unroll
    for (int s = 0; s < MS; ++s) {
        const float* g = srcbase + (size_t)s * (NB * SS);
        // Stage slice s into LDS: direct global->LDS, 16B per lane, linear.
        gload_lds16(g + 4 * tid,              smem + 4 * tid);
        gload_lds16(g + 4 * (tid + NTHR),     smem + 4 * (tid + NTHR));
        if (tid < NF4 - 2 * NTHR)
            gload_lds16(g + 4 * (tid + 2 * NTHR), smem + 4 * (tid + 2 * NTHR));
        __syncthreads();   // drains vmcnt -> LDS slice ready

        const float bxs = bx[s], bys = by[s];
        #pragma unroll
        for (int j = 0; j < 3; ++j) {
            if (j == 2 && !hasc[2]) break;
            // y-side geometry, once per chunk
            float iy = fmaf((float)ys[j], A, bys);
            float iy0f = floorf(iy);
            float wy1 = iy - iy0f;
            float wy0 = 1.0f - wy1;
            int iy0 = (int)iy0f;
            int iy1 = iy0 + 1;
            float wya = ((unsigned)iy0 <= 51u) ? wy0 : 0.0f;
            float wyb = ((unsigned)iy1 <= 51u) ? wy1 : 0.0f;
            const float* r0 = smem + min(max(iy0, 0), SL - 1) * SL;
            const float* r1 = smem + min(max(iy1, 0), SL - 1) * SL;
            #pragma unroll
            for (int k = 0; k < 4; ++k) {
                float ix = fmaf((float)(xs[j] + k), A, bxs);
                float ix0f = floorf(ix);
                float wx1 = ix - ix0f;
                float wx0 = 1.0f - wx1;
                int ix0 = (int)ix0f;
                int ix1 = ix0 + 1;
                float wxa = ((unsigned)ix0 <= 51u) ? wx0 : 0.0f;
                float wxb = ((unsigned)ix1 <= 51u) ? wx1 : 0.0f;
                int ix0c = min(max(ix0, 0), SL - 1);
                int ix1c = min(max(ix1, 0), SL - 1);
                float h0 = r0[ix0c] * wxa + r0[ix1c] * wxb;
                float h1 = r1[ix0c] * wxa + r1[ix1c] * wxb;
                acc[j][k] = fmaf(h0, wya, acc[j][k]);
                acc[j][k] = fmaf(h1, wyb, acc[j][k]);
            }
        }
        __syncthreads();   // protect smem before next stage overwrites
    }

    float* outp = out + ((size_t)p * NB + b) * SS;
    #pragma unroll
    for (int j = 0; j < 3; ++j) {
        if (j == 2 && !hasc[2]) break;
        float4 v = make_float4(acc[j][0], acc[j][1], acc[j][2], acc[j][3]);
        *reinterpret_cast<float4*>(outp + ys[j] * SL + xs[j]) = v;
    }
}

extern "C" void kernel_launch(void* const* d_in, const int* in_sizes, int n_in,
                              void* d_out, int out_size, void* d_ws, size_t ws_size,
                              hipStream_t stream) {
    const float* locs = (const float*)d_in[0];
    const float* sources = (const float*)d_in[1];
    float* out = (float*)d_out;
    dim3 grid(NP * NB);
    dim3 block(NTHR);
    hipLaunchKernelGGL(tile_render_kernel, grid, block, 0, stream,
                       locs, sources, out);
}

// Round 3
// 56.126 us; speedup vs baseline: 1.5693x; 1.2388x over previous
//
#include <hip/hip_runtime.h>

// TileRenderer: out[p,b,y,x] = sum_s bilinear_sample(sources[p,s,b], affine(locs[p,s]))
// n_ptiles=1024, max_src=4, n_bands=5, ptile_slen=52.
//
// Affine derivation (exact in real arithmetic):
//   l  = (loc*(4/52) + 24/52 - 0.5)*2
//   ix = x*(25.5/26) + (1-l1)*25.5 - 25.5^2/26   (grid[...,0] uses swapped l)
//   iy = y*(25.5/26) + (1-l0)*25.5 - 25.5^2/26
// ix ranges over [-2.5, 52.5] for locs in [0,1] -> ix0 in [-3,52]; all
// out-of-range corners get weight 0, reads are kept in-bounds via a
// clamp-to-[-1,51] pair base plus 4-float front pad and 4-float tail pad.
constexpr int NP = 1024;
constexpr int MS = 4;
constexpr int NB = 5;
constexpr int SL = 52;
constexpr int SS = SL * SL;   // 2704
constexpr int NF4 = SS / 4;   // 676
constexpr int NTHR = 256;
constexpr int NJ = (SS + NTHR - 1) / NTHR;  // 11 pixels per thread (last partial)
constexpr int BUF = SS + 4;   // + tail pad, 2708 floats = 10832 B (16B-mult)

__device__ __forceinline__ void gload_lds16(const float* g, float* l) {
    __builtin_amdgcn_global_load_lds(
        (const __attribute__((address_space(1))) void*)g,
        (__attribute__((address_space(3))) void*)l,
        16, 0, 0);
}

__global__ __launch_bounds__(NTHR) void tile_render_kernel(
    const float* __restrict__ locs,
    const float* __restrict__ sources,
    float* __restrict__ out)
{
    // [front pad 4][buf0 2708][buf1 2708] -> 21680 B -> 7 blocks/CU
    __shared__ __align__(16) float smem[4 + 2 * BUF];
    float* const buf0 = smem + 4;
    float* const buf1 = smem + 4 + BUF;

    const int blk = blockIdx.x;
    const int p = blk / NB;
    const int b = blk - p * NB;
    const int tid = threadIdx.x;

    const float A = 25.5f / 26.0f;
    float bx[MS], by[MS];
    #pragma unroll
    for (int s = 0; s < MS; ++s) {
        float loc0 = locs[(p * MS + s) * 2 + 0];
        float loc1 = locs[(p * MS + s) * 2 + 1];
        float l0 = (loc0 * (4.0f / 52.0f) + (24.0f / 52.0f) - 0.5f) * 2.0f;
        float l1 = (loc1 * (4.0f / 52.0f) + (24.0f / 52.0f) - 0.5f) * 2.0f;
        bx[s] = (1.0f - l1) * 25.5f - 25.5f * 25.5f / 26.0f;
        by[s] = (1.0f - l0) * 25.5f - 25.5f * 25.5f / 26.0f;
    }

    const float* srcbase = sources + (size_t)p * MS * NB * SS + (size_t)b * SS;

    auto stage = [&](float* dst, int s) {
        const float* g = srcbase + (size_t)s * (NB * SS);
        gload_lds16(g + 4 * tid,          dst + 4 * tid);
        gload_lds16(g + 4 * (tid + NTHR), dst + 4 * (tid + NTHR));
        if (tid < NF4 - 2 * NTHR)
            gload_lds16(g + 4 * (tid + 2 * NTHR), dst + 4 * (tid + 2 * NTHR));
    };

    float acc[NJ];
    #pragma unroll
    for (int j = 0; j < NJ; ++j) acc[j] = 0.0f;

    stage(buf0, 0);

    #pragma unroll
    for (int s = 0; s < MS; ++s) {
        float* const cur = (s & 1) ? buf1 : buf0;
        float* const nxt = (s & 1) ? buf0 : buf1;
        // Barrier drains vmcnt: cur's stage complete; also everyone is done
        // reading nxt (staged loads issued below had the whole previous
        // compute phase to land before the NEXT barrier drains them).
        __syncthreads();
        if (s < MS - 1) stage(nxt, s + 1);

        const float bxs = bx[s], bys = by[s];
        #pragma unroll
        for (int j = 0; j < NJ; ++j) {
            int pix = tid + j * NTHR;
            if (j == NJ - 1 && pix >= SS) continue;
            int y = pix / SL;
            int x = pix - y * SL;
            float ix = fmaf((float)x, A, bxs);
            float iy = fmaf((float)y, A, bys);
            float ix0f = floorf(ix);
            float iy0f = floorf(iy);
            float wx1 = ix - ix0f;
            float wy1 = iy - iy0f;
            float wx0 = 1.0f - wx1;
            float wy0 = 1.0f - wy1;
            int ix0 = (int)ix0f;
            int iy0 = (int)iy0f;
            float wxa = ((unsigned)ix0       <= 51u) ? wx0 : 0.0f;
            float wxb = ((unsigned)(ix0 + 1) <= 51u) ? wx1 : 0.0f;
            float wya = ((unsigned)iy0       <= 51u) ? wy0 : 0.0f;
            float wyb = ((unsigned)(iy0 + 1) <= 51u) ? wy1 : 0.0f;
            // Pair base: clamp to [-1, 51] so {base, base+1} always covers
            // every corner that has nonzero weight; OOB half is masked.
            int bxi = min(max(ix0, -1), SL - 1);
            int r0 = min(max(iy0, 0), SL - 1);
            int r1 = min(max(iy0 + 1, 0), SL - 1);
            const float* p0 = cur + r0 * SL + bxi;
            const float* p1 = cur + r1 * SL + bxi;
            // adjacent pairs, shared base -> ds_read2_b32
            float v00 = p0[0], v01 = p0[1];
            float v10 = p1[0], v11 = p1[1];
            float h0 = fmaf(v01, wxb, v00 * wxa);
            float h1 = fmaf(v11, wxb, v10 * wxa);
            acc[j] = fmaf(h0, wya, acc[j]);
            acc[j] = fmaf(h1, wyb, acc[j]);
        }
    }

    float* outp = out + ((size_t)p * NB + b) * SS;
    #pragma unroll
    for (int j = 0; j < NJ; ++j) {
        int pix = tid + j * NTHR;
        if (pix < SS) outp[pix] = acc[j];
    }
}

extern "C" void kernel_launch(void* const* d_in, const int* in_sizes, int n_in,
                              void* d_out, int out_size, void* d_ws, size_t ws_size,
                              hipStream_t stream) {
    const float* locs = (const float*)d_in[0];
    const float* sources = (const float*)d_in[1];
    float* out = (float*)d_out;
    dim3 grid(NP * NB);
    dim3 block(NTHR);
    hipLaunchKernelGGL(tile_render_kernel, grid, block, 0, stream,
                       locs, sources, out);
}